// Round 1
// baseline (151.716 us; speedup 1.0000x reference)
//
#include <hip/hip_runtime.h>
#include <math.h>

#define PMAX 22
#define HID 64
#define OUTD 128
#define SETS_PER_WAVE 8
#define WAVES_PER_BLOCK 4

__global__ __launch_bounds__(256) void set_encoder_kernel(
    const float* __restrict__ player_locs,  // [B,22,2]
    const float* __restrict__ actor_locs,   // [B,2]
    const float* __restrict__ flags,        // [B,22,2]
    const int*   __restrict__ mask,         // [B,22]
    const float* __restrict__ W1,           // [6,64]
    const float* __restrict__ b1,           // [64]
    const float* __restrict__ W2,           // [64,128]
    const float* __restrict__ b2,           // [128]
    float* __restrict__ out)                // [B,128]
{
    __shared__ float w2s[HID * OUTD];                              // 32 KB
    __shared__ float feats[WAVES_PER_BLOCK][PMAX][8];              // 2.75 KB
    __shared__ float hbars[WAVES_PER_BLOCK][HID][SETS_PER_WAVE];   // 8 KB

    const int tid  = threadIdx.x;
    const int lane = tid & 63;
    const int wave = tid >> 6;

    // --- cooperative W2 -> LDS (coalesced float4) ---
    {
        const float4* src = (const float4*)W2;
        float4*       dst = (float4*)w2s;
#pragma unroll
        for (int i = 0; i < 8; ++i) dst[i * 256 + tid] = src[i * 256 + tid];
    }

    // --- per-lane W1 column + bias (lane = hidden unit) ---
    const float w10 = W1[0 * HID + lane];
    const float w11 = W1[1 * HID + lane];
    const float w12 = W1[2 * HID + lane];
    const float w13 = W1[3 * HID + lane];
    const float w14 = W1[4 * HID + lane];
    const float w15 = W1[5 * HID + lane];
    const float b1l = b1[lane];

    const int wave_id = blockIdx.x * WAVES_PER_BLOCK + wave;
    const int set0    = wave_id * SETS_PER_WAVE;

    unsigned nonempty = 0;  // bit s => cnt>0 for set s

    __syncthreads();  // W2 staged

    // --- phase 1: feats + layer1 + masked pool, per set ---
    for (int s = 0; s < SETS_PER_WAVE; ++s) {
        const int b = set0 + s;
        if (lane < PMAX) {
            float2 pl = ((const float2*)player_locs)[b * PMAX + lane];
            float2 ac = ((const float2*)actor_locs)[b];
            float2 fl = ((const float2*)flags)[b * PMAX + lane];
            int    m  = mask[b * PMAX + lane];
            float dx = pl.x - ac.x;
            float dy = pl.y - ac.y;
            float dist = sqrtf(dx * dx + dy * dy);
            float ang  = atan2f(dy, dx);
            float4* fr = (float4*)&feats[wave][lane][0];
            fr[0] = make_float4(dx, dy, dist, ang);
            fr[1] = make_float4(fl.x, fl.y, (float)m, 0.0f);
        }
        __syncthreads();

        float acc = 0.0f, cnt = 0.0f;
#pragma unroll
        for (int p = 0; p < PMAX; ++p) {
            float4 fA = *(const float4*)&feats[wave][p][0];
            float4 fB = *(const float4*)&feats[wave][p][4];
            float h = b1l;
            h = fmaf(fA.x, w10, h);
            h = fmaf(fA.y, w11, h);
            h = fmaf(fA.z, w12, h);
            h = fmaf(fA.w, w13, h);
            h = fmaf(fB.x, w14, h);
            h = fmaf(fB.y, w15, h);
            h = fmaxf(h, 0.0f);
            acc = fmaf(fB.z, h, acc);
            cnt += fB.z;
        }
        const float scale = 1.0f / fmaxf(cnt, 1.0f);
        hbars[wave][lane][s] = acc * scale;
        if (cnt > 0.0f) nonempty |= (1u << s);
        __syncthreads();  // feats WAR for next s; hbars visibility after last s
    }

    // --- phase 2: out[8 sets][2 cols per lane] = hbar @ W2 ---
    float a0[SETS_PER_WAVE], a1[SETS_PER_WAVE];
#pragma unroll
    for (int s = 0; s < SETS_PER_WAVE; ++s) { a0[s] = 0.0f; a1[s] = 0.0f; }

#pragma unroll 8
    for (int k = 0; k < HID; ++k) {
        float2 w2v = *(const float2*)&w2s[k * OUTD + 2 * lane];
        float4 h0  = *(const float4*)&hbars[wave][k][0];  // sets 0..3 (broadcast)
        float4 h1  = *(const float4*)&hbars[wave][k][4];  // sets 4..7 (broadcast)
        a0[0] = fmaf(h0.x, w2v.x, a0[0]); a1[0] = fmaf(h0.x, w2v.y, a1[0]);
        a0[1] = fmaf(h0.y, w2v.x, a0[1]); a1[1] = fmaf(h0.y, w2v.y, a1[1]);
        a0[2] = fmaf(h0.z, w2v.x, a0[2]); a1[2] = fmaf(h0.z, w2v.y, a1[2]);
        a0[3] = fmaf(h0.w, w2v.x, a0[3]); a1[3] = fmaf(h0.w, w2v.y, a1[3]);
        a0[4] = fmaf(h1.x, w2v.x, a0[4]); a1[4] = fmaf(h1.x, w2v.y, a1[4]);
        a0[5] = fmaf(h1.y, w2v.x, a0[5]); a1[5] = fmaf(h1.y, w2v.y, a1[5]);
        a0[6] = fmaf(h1.z, w2v.x, a0[6]); a1[6] = fmaf(h1.z, w2v.y, a1[6]);
        a0[7] = fmaf(h1.w, w2v.x, a0[7]); a1[7] = fmaf(h1.w, w2v.y, a1[7]);
    }

    // --- epilogue: + b2 * [cnt>0], coalesced float2 stores ---
    const float2 b2v = *(const float2*)&b2[2 * lane];
#pragma unroll
    for (int s = 0; s < SETS_PER_WAVE; ++s) {
        const float f = (nonempty >> s) & 1u ? 1.0f : 0.0f;
        float2 o;
        o.x = a0[s] + f * b2v.x;
        o.y = a1[s] + f * b2v.y;
        ((float2*)out)[(size_t)(set0 + s) * (OUTD / 2) + lane] = o;
    }
}

extern "C" void kernel_launch(void* const* d_in, const int* in_sizes, int n_in,
                              void* d_out, int out_size, void* d_ws, size_t ws_size,
                              hipStream_t stream) {
    const float* player_locs = (const float*)d_in[0];
    const float* actor_locs  = (const float*)d_in[1];
    const float* flags       = (const float*)d_in[2];
    const int*   mask        = (const int*)d_in[3];
    const float* W1          = (const float*)d_in[4];
    const float* b1          = (const float*)d_in[5];
    const float* W2          = (const float*)d_in[6];
    const float* b2          = (const float*)d_in[7];
    float*       out         = (float*)d_out;

    const int B = in_sizes[0] / (PMAX * 2);  // 65536
    const int sets_per_block = WAVES_PER_BLOCK * SETS_PER_WAVE;  // 32
    const int grid = (B + sets_per_block - 1) / sets_per_block;  // 2048

    hipLaunchKernelGGL(set_encoder_kernel, dim3(grid), dim3(256), 0, stream,
                       player_locs, actor_locs, flags, mask, W1, b1, W2, b2, out);
}

// Round 2
// 135.289 us; speedup vs baseline: 1.1214x; 1.1214x over previous
//
#include <hip/hip_runtime.h>
#include <math.h>

#define PMAX 22
#define HID 64
#define OUTD 128
#define SETS_PER_WAVE 8
#define WAVES_PER_BLOCK 4
#define ROWS (PMAX * SETS_PER_WAVE)  // 176 player-rows per wave

// Wave-internal LDS sync: all lanes of a wave are lockstep (single PC), so
// after this every lane's ds_write has completed before any subsequent
// ds_read issues. No cross-wave LDS sharing in this kernel -> no __syncthreads.
__device__ __forceinline__ void wave_lds_sync() {
    asm volatile("s_waitcnt lgkmcnt(0)" ::: "memory");
    __builtin_amdgcn_wave_barrier();
}

__global__ __launch_bounds__(256) void set_encoder_kernel(
    const float* __restrict__ player_locs,  // [B,22,2]
    const float* __restrict__ actor_locs,   // [B,2]
    const float* __restrict__ flags,        // [B,22,2]
    const int*   __restrict__ mask,         // [B,22]
    const float* __restrict__ W1,           // [6,64]
    const float* __restrict__ b1,           // [64]
    const float* __restrict__ W2,           // [64,128]
    const float* __restrict__ b2,           // [128]
    float* __restrict__ out)                // [B,128]
{
    __shared__ float feats[WAVES_PER_BLOCK][ROWS][8];                // 22 KB
    __shared__ float hbars[WAVES_PER_BLOCK][HID][SETS_PER_WAVE];     // 8 KB

    const int tid  = threadIdx.x;
    const int lane = tid & 63;
    const int wave = tid >> 6;

    const int wave_id = blockIdx.x * WAVES_PER_BLOCK + wave;
    const int set0    = wave_id * SETS_PER_WAVE;
    const int row0    = set0 * PMAX;  // global player-row of this wave's first row

    // --- per-lane W1 column + bias (lane = hidden unit) ---
    const float w10 = W1[0 * HID + lane];
    const float w11 = W1[1 * HID + lane];
    const float w12 = W1[2 * HID + lane];
    const float w13 = W1[3 * HID + lane];
    const float w14 = W1[4 * HID + lane];
    const float w15 = W1[5 * HID + lane];
    const float b1l = b1[lane];

    // --- phase 0: features for all 8 sets, full-lane, coalesced ---
#pragma unroll
    for (int i = 0; i < 3; ++i) {
        const int idx = lane + 64 * i;  // 0..175 (i==2: lanes 0..47)
        if (idx < ROWS) {
            const int s = idx / PMAX;  // set within wave (magic-mul)
            float2 pl = ((const float2*)player_locs)[row0 + idx];
            float2 fl = ((const float2*)flags)[row0 + idx];
            int    m  = mask[row0 + idx];
            float2 ac = ((const float2*)actor_locs)[set0 + s];
            float dx = pl.x - ac.x;
            float dy = pl.y - ac.y;
            float dist = sqrtf(dx * dx + dy * dy);
            float ang  = atan2f(dy, dx);
            float4* fr = (float4*)&feats[wave][idx][0];
            fr[0] = make_float4(dx, dy, dist, ang);
            fr[1] = make_float4(fl.x, fl.y, (float)m, 0.0f);
        }
    }
    wave_lds_sync();

    // --- phase 1: layer1 + masked pool; lane = hidden unit ---
    unsigned nonempty = 0;
    for (int s = 0; s < SETS_PER_WAVE; ++s) {
        const float* fb = &feats[wave][s * PMAX][0];
        float acc = 0.0f, cnt = 0.0f;
#pragma unroll
        for (int p = 0; p < PMAX; ++p) {
            float4 fA = *(const float4*)(fb + p * 8);
            float4 fB = *(const float4*)(fb + p * 8 + 4);
            float h = b1l;
            h = fmaf(fA.x, w10, h);
            h = fmaf(fA.y, w11, h);
            h = fmaf(fA.z, w12, h);
            h = fmaf(fA.w, w13, h);
            h = fmaf(fB.x, w14, h);
            h = fmaf(fB.y, w15, h);
            h = fmaxf(h, 0.0f);
            acc = fmaf(fB.z, h, acc);
            cnt += fB.z;
        }
        const float scale = 1.0f / fmaxf(cnt, 1.0f);
        hbars[wave][lane][s] = acc * scale;
        if (cnt > 0.0f) nonempty |= (1u << s);
    }
    wave_lds_sync();

    // --- phase 2: out[8 sets][2 cols/lane] = hbar @ W2; W2 via L1/L2 ---
    float a0[SETS_PER_WAVE], a1[SETS_PER_WAVE];
#pragma unroll
    for (int s = 0; s < SETS_PER_WAVE; ++s) { a0[s] = 0.0f; a1[s] = 0.0f; }

    const float2* w2p = (const float2*)W2;  // [64][64] float2; lane owns col pair
#pragma unroll 8
    for (int k = 0; k < HID; ++k) {
        float2 w2v = w2p[k * 64 + lane];
        float4 h0  = *(const float4*)&hbars[wave][k][0];  // sets 0..3 (broadcast)
        float4 h1  = *(const float4*)&hbars[wave][k][4];  // sets 4..7 (broadcast)
        a0[0] = fmaf(h0.x, w2v.x, a0[0]); a1[0] = fmaf(h0.x, w2v.y, a1[0]);
        a0[1] = fmaf(h0.y, w2v.x, a0[1]); a1[1] = fmaf(h0.y, w2v.y, a1[1]);
        a0[2] = fmaf(h0.z, w2v.x, a0[2]); a1[2] = fmaf(h0.z, w2v.y, a1[2]);
        a0[3] = fmaf(h0.w, w2v.x, a0[3]); a1[3] = fmaf(h0.w, w2v.y, a1[3]);
        a0[4] = fmaf(h1.x, w2v.x, a0[4]); a1[4] = fmaf(h1.x, w2v.y, a1[4]);
        a0[5] = fmaf(h1.y, w2v.x, a0[5]); a1[5] = fmaf(h1.y, w2v.y, a1[5]);
        a0[6] = fmaf(h1.z, w2v.x, a0[6]); a1[6] = fmaf(h1.z, w2v.y, a1[6]);
        a0[7] = fmaf(h1.w, w2v.x, a0[7]); a1[7] = fmaf(h1.w, w2v.y, a1[7]);
    }

    // --- epilogue: + b2 * [cnt>0], coalesced float2 stores ---
    const float2 b2v = *(const float2*)&b2[2 * lane];
#pragma unroll
    for (int s = 0; s < SETS_PER_WAVE; ++s) {
        const float f = (nonempty >> s) & 1u ? 1.0f : 0.0f;
        float2 o;
        o.x = a0[s] + f * b2v.x;
        o.y = a1[s] + f * b2v.y;
        ((float2*)out)[(size_t)(set0 + s) * (OUTD / 2) + lane] = o;
    }
}

extern "C" void kernel_launch(void* const* d_in, const int* in_sizes, int n_in,
                              void* d_out, int out_size, void* d_ws, size_t ws_size,
                              hipStream_t stream) {
    const float* player_locs = (const float*)d_in[0];
    const float* actor_locs  = (const float*)d_in[1];
    const float* flags       = (const float*)d_in[2];
    const int*   mask        = (const int*)d_in[3];
    const float* W1          = (const float*)d_in[4];
    const float* b1          = (const float*)d_in[5];
    const float* W2          = (const float*)d_in[6];
    const float* b2          = (const float*)d_in[7];
    float*       out         = (float*)d_out;

    const int B = in_sizes[0] / (PMAX * 2);  // 65536
    const int sets_per_block = WAVES_PER_BLOCK * SETS_PER_WAVE;  // 32
    const int grid = (B + sets_per_block - 1) / sets_per_block;  // 2048

    hipLaunchKernelGGL(set_encoder_kernel, dim3(grid), dim3(256), 0, stream,
                       player_locs, actor_locs, flags, mask, W1, b1, W2, b2, out);
}

// Round 3
// 120.575 us; speedup vs baseline: 1.2583x; 1.1220x over previous
//
#include <hip/hip_runtime.h>
#include <math.h>

#define PMAX 22
#define HID 64
#define OUTD 128
#define SETS_PER_WAVE 8
#define WAVES_PER_BLOCK 4
#define ROWS (PMAX * SETS_PER_WAVE)  // 176 player-rows per wave

// Wave-internal LDS sync: lanes of a wave are lockstep; drain LDS ops so
// subsequent reads see prior writes. No cross-wave LDS sharing here.
__device__ __forceinline__ void wave_lds_sync() {
    asm volatile("s_waitcnt lgkmcnt(0)" ::: "memory");
    __builtin_amdgcn_wave_barrier();
}

__global__ __launch_bounds__(256) void set_encoder_kernel(
    const float* __restrict__ player_locs,  // [B,22,2]
    const float* __restrict__ actor_locs,   // [B,2]
    const float* __restrict__ flags,        // [B,22,2]
    const int*   __restrict__ mask,         // [B,22]
    const float* __restrict__ W1,           // [6,64]
    const float* __restrict__ b1,           // [64]
    const float* __restrict__ W2,           // [64,128]
    const float* __restrict__ b2,           // [128]
    float* __restrict__ out)                // [B,128]
{
    __shared__ float feats[WAVES_PER_BLOCK][ROWS][8];              // 22 KB
    __shared__ float hbars[WAVES_PER_BLOCK][HID][SETS_PER_WAVE];   // 8 KB

    const int tid  = threadIdx.x;
    const int lane = tid & 63;
    const int wave = tid >> 6;

    const int wave_id = blockIdx.x * WAVES_PER_BLOCK + wave;
    const int set0    = wave_id * SETS_PER_WAVE;
    const int row0    = set0 * PMAX;

    // --- per-lane W1 column + bias (lane = hidden unit) ---
    const float w10 = W1[0 * HID + lane];
    const float w11 = W1[1 * HID + lane];
    const float w12 = W1[2 * HID + lane];
    const float w13 = W1[3 * HID + lane];
    const float w14 = W1[4 * HID + lane];
    const float w15 = W1[5 * HID + lane];
    const float b1l = b1[lane];

    // --- phase 0: features for 176 rows, full-lane, coalesced; build a
    //     176-bit validity bitmap via 3 ballots (bit l of ballot i = row 64i+l)
    unsigned long long bm[3];
#pragma unroll
    for (int i = 0; i < 3; ++i) {
        const int idx  = lane + 64 * i;
        const int ridx = idx < ROWS ? idx : ROWS - 1;  // clamp: safe OOB guard
        float2 pl = ((const float2*)player_locs)[row0 + ridx];
        float2 fl = ((const float2*)flags)[row0 + ridx];
        int    m  = mask[row0 + ridx];
        const int s = ridx / PMAX;
        float2 ac = ((const float2*)actor_locs)[set0 + s];
        float dx = pl.x - ac.x;
        float dy = pl.y - ac.y;
        float dist = sqrtf(dx * dx + dy * dy);
        float ang  = atan2f(dy, dx);
        bm[i] = __ballot((idx < ROWS) && (m != 0));
        if (idx < ROWS) {
            float4* fr = (float4*)&feats[wave][ridx][0];
            fr[0] = make_float4(dx, dy, dist, ang);
            fr[1] = make_float4(fl.x, fl.y, 0.0f, 0.0f);
        }
    }
    wave_lds_sync();

    // --- phase 1: layer1 + masked pool; lane = hidden unit.
    //     Scalar (SGPR) player bitmask per set -> uniform s_cbranch loop that
    //     only visits valid players; cnt comes free from popcount.
    unsigned nonempty = 0;
#pragma unroll
    for (int s = 0; s < SETS_PER_WAVE; ++s) {
        const int start = PMAX * s;
        const int w = start >> 6, r = start & 63;
        unsigned long long lo = bm[w] >> r;
        if (r > 64 - PMAX) lo |= bm[w + 1] << (64 - r);
        unsigned bits = (unsigned)lo & 0x3FFFFFu;

        const int cnt = __builtin_popcount(bits);
        if (bits) nonempty |= (1u << s);

        const float* fb = &feats[wave][start][0];
        float acc = 0.0f;
        unsigned bb = bits;
        while (bb) {
            const int p = __builtin_ctz(bb);
            bb &= bb - 1;
            const float* fp = fb + (p << 3);
            float4 fA = *(const float4*)fp;
            float2 fB = *(const float2*)(fp + 4);
            float t0 = fmaf(fA.x, w10, b1l);
            t0 = fmaf(fA.y, w11, t0);
            t0 = fmaf(fA.z, w12, t0);
            float t1 = fA.w * w13;
            t1 = fmaf(fB.x, w14, t1);
            t1 = fmaf(fB.y, w15, t1);
            acc += fmaxf(t0 + t1, 0.0f);
        }
        const float scale = 1.0f / fmaxf((float)cnt, 1.0f);
        hbars[wave][lane][s] = acc * scale;
    }
    wave_lds_sync();

    // --- phase 2: out[8 sets][2 cols/lane] = hbar @ W2; W2 via L1/L2 ---
    float a0[SETS_PER_WAVE], a1[SETS_PER_WAVE];
#pragma unroll
    for (int s = 0; s < SETS_PER_WAVE; ++s) { a0[s] = 0.0f; a1[s] = 0.0f; }

    const float2* w2p = (const float2*)W2;  // [64][64] float2; lane owns col pair
#pragma unroll 8
    for (int k = 0; k < HID; ++k) {
        float2 w2v = w2p[k * 64 + lane];
        float4 h0  = *(const float4*)&hbars[wave][k][0];  // sets 0..3 (broadcast)
        float4 h1  = *(const float4*)&hbars[wave][k][4];  // sets 4..7 (broadcast)
        a0[0] = fmaf(h0.x, w2v.x, a0[0]); a1[0] = fmaf(h0.x, w2v.y, a1[0]);
        a0[1] = fmaf(h0.y, w2v.x, a0[1]); a1[1] = fmaf(h0.y, w2v.y, a1[1]);
        a0[2] = fmaf(h0.z, w2v.x, a0[2]); a1[2] = fmaf(h0.z, w2v.y, a1[2]);
        a0[3] = fmaf(h0.w, w2v.x, a0[3]); a1[3] = fmaf(h0.w, w2v.y, a1[3]);
        a0[4] = fmaf(h1.x, w2v.x, a0[4]); a1[4] = fmaf(h1.x, w2v.y, a1[4]);
        a0[5] = fmaf(h1.y, w2v.x, a0[5]); a1[5] = fmaf(h1.y, w2v.y, a1[5]);
        a0[6] = fmaf(h1.z, w2v.x, a0[6]); a1[6] = fmaf(h1.z, w2v.y, a1[6]);
        a0[7] = fmaf(h1.w, w2v.x, a0[7]); a1[7] = fmaf(h1.w, w2v.y, a1[7]);
    }

    // --- epilogue: + b2 * [cnt>0], coalesced float2 stores ---
    const float2 b2v = *(const float2*)&b2[2 * lane];
#pragma unroll
    for (int s = 0; s < SETS_PER_WAVE; ++s) {
        const float f = (nonempty >> s) & 1u ? 1.0f : 0.0f;
        float2 o;
        o.x = a0[s] + f * b2v.x;
        o.y = a1[s] + f * b2v.y;
        ((float2*)out)[(size_t)(set0 + s) * (OUTD / 2) + lane] = o;
    }
}

extern "C" void kernel_launch(void* const* d_in, const int* in_sizes, int n_in,
                              void* d_out, int out_size, void* d_ws, size_t ws_size,
                              hipStream_t stream) {
    const float* player_locs = (const float*)d_in[0];
    const float* actor_locs  = (const float*)d_in[1];
    const float* flags       = (const float*)d_in[2];
    const int*   mask        = (const int*)d_in[3];
    const float* W1          = (const float*)d_in[4];
    const float* b1          = (const float*)d_in[5];
    const float* W2          = (const float*)d_in[6];
    const float* b2          = (const float*)d_in[7];
    float*       out         = (float*)d_out;

    const int B = in_sizes[0] / (PMAX * 2);  // 65536
    const int sets_per_block = WAVES_PER_BLOCK * SETS_PER_WAVE;  // 32
    const int grid = (B + sets_per_block - 1) / sets_per_block;  // 2048

    hipLaunchKernelGGL(set_encoder_kernel, dim3(grid), dim3(256), 0, stream,
                       player_locs, actor_locs, flags, mask, W1, b1, W2, b2, out);
}